// Round 1
// baseline (608.307 us; speedup 1.0000x reference)
//
#include <hip/hip_runtime.h>

typedef __bf16 bf16_t;
typedef bf16_t bf16x8 __attribute__((ext_vector_type(8)));
typedef float f32x4 __attribute__((ext_vector_type(4)));
typedef unsigned short u16;

#define T_DIM 2048
#define N_DIM 1024
#define D_DIM 128
#define BH_DIM 16

__device__ __forceinline__ u16 f32_to_bf16(float f) {
    unsigned int u = __builtin_bit_cast(unsigned int, f);
    u += 0x7FFFu + ((u >> 16) & 1u);   // round-to-nearest-even
    return (u16)(u >> 16);
}

// ---- Kernel 1: RoPE on Q + cast to bf16. One thread per (even,odd) pair. ----
__global__ void rope_kernel(const float* __restrict__ Q, u16* __restrict__ QR) {
    const int idx = blockIdx.x * 256 + threadIdx.x;   // pair index, 16,777,216 total
    const int row = idx >> 9;                         // 512 pairs per length-1024 row
    const int p   = idx & 511;
    const int t   = row & (T_DIM - 1);
    // freq = THETA^(-2p/1024)/(2pi) = 2^(-p/32)/(2pi)
    const float freq = exp2f((float)p * (-1.0f / 32.0f)) * 0.15915494309189535f;
    float ph = (float)t * freq;
    ph = (ph - floorf(ph)) * 6.283185307179586f;
    float s, c;
    sincosf(ph, &s, &c);
    const float2 q = ((const float2*)Q)[idx];
    ushort2 o;
    o.x = f32_to_bf16(q.x * c - q.y * s);   // out[2i]   = q[2i]*c - q[2i+1]*s
    o.y = f32_to_bf16(q.y * c + q.x * s);   // out[2i+1] = q[2i+1]*c + q[2i]*s
    ((ushort2*)QR)[idx] = o;
}

// ---- Kernel 2: V -> bf16, transposed to Vt[bh][d][t] via LDS tile ----
__global__ void vt_kernel(const float* __restrict__ V, u16* __restrict__ Vt) {
    __shared__ u16 tile[64][65];
    const int bh   = blockIdx.x >> 6;
    const int rem  = blockIdx.x & 63;
    const int tblk = rem >> 1;
    const int dblk = rem & 1;
    const int t0 = tblk * 64, d0 = dblk * 64;
    const float* src = V + ((size_t)bh * T_DIM + t0) * D_DIM + d0;
    #pragma unroll
    for (int k = 0; k < 16; ++k) {
        int linear = k * 256 + threadIdx.x;
        int r = linear >> 6, c = linear & 63;
        tile[r][c] = f32_to_bf16(src[(size_t)r * D_DIM + c]);
    }
    __syncthreads();
    u16* dst = Vt + ((size_t)bh * D_DIM + d0) * T_DIM + t0;
    #pragma unroll
    for (int k = 0; k < 16; ++k) {
        int linear = k * 256 + threadIdx.x;
        int dr = linear >> 6, tc = linear & 63;
        dst[(size_t)dr * T_DIM + tc] = tile[tc][dr];
    }
}

// ---- Kernel 3: core. One block = (bh, q-tile of 128, half of key range). ----
// S = QRq @ QRk^T (bf16 MFMA, K=1024), strict-causal mask on diagonal tile,
// P->LDS (layout transform), O += P @ V via Vt fragments from global (L2).
__global__ __launch_bounds__(256, 2)
void attn_kernel(const u16* __restrict__ QR, const u16* __restrict__ Vt,
                 float* __restrict__ Out, float* __restrict__ Opart) {
    // As/Bs (staging, 128x72 u16 each) unioned with Ps (128x136 u16). 36,864 B.
    __shared__ __align__(16) u16 Smem[18432];
    u16 (*As)[72]  = (u16 (*)[72])Smem;
    u16 (*Bs)[72]  = (u16 (*)[72])(Smem + 9216);
    u16 (*Ps)[136] = (u16 (*)[136])Smem;

    // long q-tiles first (LPT scheduling for the 2-blocks/CU backfill)
    const int qt   = 15 - (blockIdx.x >> 5);
    const int half = (blockIdx.x >> 4) & 1;
    const int bh   = blockIdx.x & 15;

    const int tid  = threadIdx.x;
    const int w    = tid >> 6;
    const int lane = tid & 63;
    const int quad = lane >> 4;
    const int l15  = lane & 15;

    const u16* QRb  = QR + (size_t)bh * T_DIM * N_DIM;
    const u16* Qrow = QRb + (size_t)qt * 128 * N_DIM;
    const u16* Vb   = Vt + (size_t)bh * D_DIM * T_DIM;

    const int jbeg = half ? ((qt + 1) >> 1) : 0;
    const int jend = half ? (qt + 1) : ((qt + 1) >> 1);

    const f32x4 fz = {0.f, 0.f, 0.f, 0.f};
    f32x4 o_acc[2][8];
    #pragma unroll
    for (int mi = 0; mi < 2; ++mi)
        #pragma unroll
        for (int nj = 0; nj < 8; ++nj)
            o_acc[mi][nj] = fz;

    for (int j = jbeg; j < jend; ++j) {
        const u16* Krow = QRb + (size_t)j * 128 * N_DIM;
        f32x4 s_acc[2][8];
        #pragma unroll
        for (int mi = 0; mi < 2; ++mi)
            #pragma unroll
            for (int nj = 0; nj < 8; ++nj)
                s_acc[mi][nj] = fz;

        __syncthreads();   // prev j's Ps reads (aliased w/ As/Bs) must be done

        for (int kk = 0; kk < N_DIM; kk += 64) {
            #pragma unroll
            for (int pp = 0; pp < 4; ++pp) {
                const int linear = pp * 256 + tid;
                const int r  = linear >> 3;
                const int c8 = (linear & 7) * 8;
                *(uint4*)(&As[r][c8]) = *(const uint4*)(Qrow + (size_t)r * N_DIM + kk + c8);
                *(uint4*)(&Bs[r][c8]) = *(const uint4*)(Krow + (size_t)r * N_DIM + kk + c8);
            }
            __syncthreads();
            #pragma unroll
            for (int kc = 0; kc < 2; ++kc) {
                const int k0 = kc * 32 + quad * 8;
                const bf16x8 a0 = *(const bf16x8*)(&As[w * 32 + l15][k0]);
                const bf16x8 a1 = *(const bf16x8*)(&As[w * 32 + 16 + l15][k0]);
                #pragma unroll
                for (int nj = 0; nj < 8; ++nj) {
                    const bf16x8 bv = *(const bf16x8*)(&Bs[nj * 16 + l15][k0]);
                    s_acc[0][nj] = __builtin_amdgcn_mfma_f32_16x16x32_bf16(a0, bv, s_acc[0][nj], 0, 0, 0);
                    s_acc[1][nj] = __builtin_amdgcn_mfma_f32_16x16x32_bf16(a1, bv, s_acc[1][nj], 0, 0, 0);
                }
            }
            __syncthreads();
        }

        if (j == qt) {   // strict causal: keep only col(s) < row(t) on the diagonal tile
            #pragma unroll
            for (int mi = 0; mi < 2; ++mi) {
                const int rowb = w * 32 + mi * 16 + quad * 4;
                #pragma unroll
                for (int nj = 0; nj < 8; ++nj) {
                    const int col = nj * 16 + l15;
                    #pragma unroll
                    for (int r = 0; r < 4; ++r)
                        if (col >= rowb + r) s_acc[mi][nj][r] = 0.f;
                }
            }
        }

        // C/D layout -> LDS (bf16). Each wave touches only its own 32 rows.
        #pragma unroll
        for (int mi = 0; mi < 2; ++mi) {
            const int rowb = w * 32 + mi * 16 + quad * 4;
            #pragma unroll
            for (int nj = 0; nj < 8; ++nj) {
                const int col = nj * 16 + l15;
                #pragma unroll
                for (int r = 0; r < 4; ++r)
                    Ps[rowb + r][col] = f32_to_bf16(s_acc[mi][nj][r]);
            }
        }
        // no barrier: each wave reads back only the Ps rows it wrote

        const u16* vjb = Vb + j * 128;
        #pragma unroll
        for (int kc = 0; kc < 4; ++kc) {
            const int k0 = kc * 32 + quad * 8;
            const bf16x8 p0 = *(const bf16x8*)(&Ps[w * 32 + l15][k0]);
            const bf16x8 p1 = *(const bf16x8*)(&Ps[w * 32 + 16 + l15][k0]);
            #pragma unroll
            for (int nj = 0; nj < 8; ++nj) {
                const bf16x8 vv = *(const bf16x8*)(vjb + (size_t)(nj * 16 + l15) * T_DIM + k0);
                o_acc[0][nj] = __builtin_amdgcn_mfma_f32_16x16x32_bf16(p0, vv, o_acc[0][nj], 0, 0, 0);
                o_acc[1][nj] = __builtin_amdgcn_mfma_f32_16x16x32_bf16(p1, vv, o_acc[1][nj], 0, 0, 0);
            }
        }
    }

    // half 1 -> Out, half 0 -> partial buffer (always written, zeros if empty range)
    float* obase = (half ? Out : Opart) + ((size_t)bh * T_DIM + (size_t)qt * 128) * D_DIM;
    #pragma unroll
    for (int mi = 0; mi < 2; ++mi)
        #pragma unroll
        for (int nj = 0; nj < 8; ++nj)
            #pragma unroll
            for (int r = 0; r < 4; ++r)
                obase[(size_t)(w * 32 + mi * 16 + quad * 4 + r) * D_DIM + nj * 16 + l15] = o_acc[mi][nj][r];
}

// ---- Kernel 4: Out += Opart ----
__global__ void combine_kernel(float* __restrict__ Out, const float* __restrict__ Part) {
    const int i = blockIdx.x * 256 + threadIdx.x;
    float4 o = ((const float4*)Out)[i];
    const float4 p = ((const float4*)Part)[i];
    o.x += p.x; o.y += p.y; o.z += p.z; o.w += p.w;
    ((float4*)Out)[i] = o;
}

extern "C" void kernel_launch(void* const* d_in, const int* in_sizes, int n_in,
                              void* d_out, int out_size, void* d_ws, size_t ws_size,
                              hipStream_t stream) {
    const float* Q = (const float*)d_in[0];
    // d_in[1] is K == Q (reference asserts identity) — unused
    const float* V = (const float*)d_in[2];

    // ws layout: QR bf16 (64 MiB) | Vt bf16 (8 MiB) | Opart f32 (16 MiB) = 92,274,688 B
    u16* QRw = (u16*)d_ws;
    u16* Vtw = QRw + (size_t)BH_DIM * T_DIM * N_DIM;
    float* Opart = (float*)(Vtw + (size_t)BH_DIM * D_DIM * T_DIM);
    float* Out = (float*)d_out;

    rope_kernel<<<dim3(65536), dim3(256), 0, stream>>>(Q, QRw);
    vt_kernel<<<dim3(1024), dim3(256), 0, stream>>>(V, Vtw);
    attn_kernel<<<dim3(512), dim3(256), 0, stream>>>(QRw, Vtw, Out, Opart);
    combine_kernel<<<dim3(4096), dim3(256), 0, stream>>>(Out, Opart);
}